// Round 4
// baseline (875.721 us; speedup 1.0000x reference)
//
#include <hip/hip_runtime.h>

#define Bsz 512
#define Ssz 512
#define Isz 32
#define Hsz 128
#define BB  2
#define LOG2E 1.44269504088896340736f

typedef __attribute__((ext_vector_type(8))) short bf16x8;
typedef __attribute__((ext_vector_type(4))) float f32x4;

__device__ __forceinline__ unsigned short f2bf(float f){
  unsigned u = __float_as_uint(f);
  return (unsigned short)((u + 0x7FFFu + ((u >> 16) & 1u)) >> 16);
}
__device__ __forceinline__ float sigm_p(float xp){          // pre-scaled by log2e
  return __builtin_amdgcn_rcpf(1.f + __builtin_amdgcn_exp2f(-xp));
}
__device__ __forceinline__ float tanh_p(float xp2){         // pre-scaled by 2*log2e
  return 1.f - 2.f * __builtin_amdgcn_rcpf(1.f + __builtin_amdgcn_exp2f(xp2));
}
__device__ __forceinline__ bf16x8 ldw(const float* p, float s){
  bf16x8 r;
#pragma unroll
  for (int e=0;e<8;++e) r[e] = (short)f2bf(p[e]*s);
  return r;
}
__device__ __forceinline__ bf16x8 ldws(const float* pa, const float* pb, float s){
  bf16x8 r;
#pragma unroll
  for (int e=0;e<8;++e) r[e] = (short)f2bf((pa[e]+pb[e])*s);
  return r;
}

__global__ __launch_bounds__(256, 1) void lstm_ae(
    const float* __restrict__ x,
    const float* __restrict__ eWih, const float* __restrict__ eWhh,
    const float* __restrict__ ebih, const float* __restrict__ ebhh,
    const float* __restrict__ dWih, const float* __restrict__ dWhh,
    const float* __restrict__ dbih, const float* __restrict__ dbhh,
    const float* __restrict__ fcW,  const float* __restrict__ fcb,
    float* __restrict__ out)
{
  __shared__ __attribute__((aligned(16))) float big[2*Ssz*Isz];     // x bf16 / frames f32
  // ping-pong h: [par][row 0..1][136] bf16 (136 shorts = 272B, keeps b128 align)
  __shared__ __attribute__((aligned(16))) unsigned short hbuf[2][2][136];

  const int tid  = threadIdx.x;
  const int lane = tid & 63;
  const int wv   = tid >> 6;
  const int c16  = lane & 15;
  const int quad = lane >> 4;
  const int bg0  = blockIdx.x * BB;
  const int hrow = c16 & 1;            // A-frag row source (rows>=2 duplicate, harmless)

  // ---- stage x as bf16 into LDS ----
  unsigned short* xl = (unsigned short*)big;
#pragma unroll 4
  for (int i = tid*4; i < 2*Ssz*Isz; i += 256*4){
    f32x4 v = *(const f32x4*)(x + (size_t)(bg0 + (i>>14))*(Ssz*Isz) + (i & 16383));
    xl[i+0]=f2bf(v[0]); xl[i+1]=f2bf(v[1]); xl[i+2]=f2bf(v[2]); xl[i+3]=f2bf(v[3]);
  }
  for (int i = tid; i < 2*2*136; i += 256) ((unsigned short*)hbuf)[i] = 0;

  // chunk slot m -> K-chunk (wv+m)&3 ; slot 0 = own 32 h-cols
  int co[4];
#pragma unroll
  for (int m=0;m<4;++m) co[m] = ((wv+m)&3)*32 + quad*8;

  // ---- encoder weights -> registers (slot-permuted) ----
  bf16x8 W[8][4], wx[8];
#pragma unroll
  for (int j=0;j<8;++j){
    int g = j>>1;
    int n = g*128 + wv*32 + (j&1)*16 + c16;
    float s = (g==2) ? 2.f*LOG2E : LOG2E;
#pragma unroll
    for (int m=0;m<4;++m)
      W[j][m] = ldw(eWhh + (size_t)n*Hsz + ((wv+m)&3)*32 + quad*8, s);
    wx[j] = ldw(eWih + (size_t)n*Isz + quad*8, s);
  }
  // act biases for this lane's cols (quad0 uses them; others load harmlessly)
  float bi[2], bff[2], bgg[2], bo[2];
#pragma unroll
  for (int hh=0;hh<2;++hh){
    int col = wv*32 + hh*16 + c16;
    bi [hh] = (ebih[0*Hsz+col]+ebhh[0*Hsz+col])*LOG2E;
    bff[hh] = (ebih[1*Hsz+col]+ebhh[1*Hsz+col])*LOG2E;
    bgg[hh] = (ebih[2*Hsz+col]+ebhh[2*Hsz+col])*(2.f*LOG2E);
    bo [hh] = (ebih[3*Hsz+col]+ebhh[3*Hsz+col])*LOG2E;
  }

  const f32x4 zero4 = {0.f,0.f,0.f,0.f};
  float cst[4] = {0.f,0.f,0.f,0.f};    // [hh*2+b] cell state, quad0 lanes

  __syncthreads();

  int par = 0;
  bf16x8 ah0 = *(const bf16x8*)(&hbuf[0][hrow][0] + co[0]);
  bf16x8 ax  = *(const bf16x8*)(xl + hrow*(Ssz*Isz) + quad*8);

  // ---------------- encoder ----------------
  for (int t=0; t<Ssz; ++t){
    const unsigned short* hp = &hbuf[par][hrow][0];
    bf16x8 ah1 = *(const bf16x8*)(hp + co[1]);
    bf16x8 ah2 = *(const bf16x8*)(hp + co[2]);
    bf16x8 ah3 = *(const bf16x8*)(hp + co[3]);
    int tn = (t+1 < Ssz) ? t+1 : t;
    bf16x8 axn = *(const bf16x8*)(xl + hrow*(Ssz*Isz) + tn*Isz + quad*8);
    f32x4 acc[8];
#pragma unroll
    for (int j=0;j<8;++j) acc[j] = __builtin_amdgcn_mfma_f32_16x16x32_bf16(ax,  wx[j],   zero4, 0,0,0);
#pragma unroll
    for (int j=0;j<8;++j) acc[j] = __builtin_amdgcn_mfma_f32_16x16x32_bf16(ah0, W[j][0], acc[j], 0,0,0);
#pragma unroll
    for (int j=0;j<8;++j) acc[j] = __builtin_amdgcn_mfma_f32_16x16x32_bf16(ah1, W[j][1], acc[j], 0,0,0);
#pragma unroll
    for (int j=0;j<8;++j) acc[j] = __builtin_amdgcn_mfma_f32_16x16x32_bf16(ah2, W[j][2], acc[j], 0,0,0);
#pragma unroll
    for (int j=0;j<8;++j) acc[j] = __builtin_amdgcn_mfma_f32_16x16x32_bf16(ah3, W[j][3], acc[j], 0,0,0);
    // act straight from acc registers (quad0 lanes own rows 0,1)
    if (quad == 0){
#pragma unroll
      for (int hh=0;hh<2;++hh){
#pragma unroll
        for (int b=0;b<2;++b){
          float pi = acc[0+hh][b] + bi [hh];
          float pf = acc[2+hh][b] + bff[hh];
          float pg = acc[4+hh][b] + bgg[hh];
          float po = acc[6+hh][b] + bo [hh];
          float iv=sigm_p(pi), fv=sigm_p(pf), ov=sigm_p(po), gv=tanh_p(pg);
          float cn = fv*cst[hh*2+b] + iv*gv;
          cst[hh*2+b] = cn;
          float hv = ov * tanh_p(cn*(2.f*LOG2E));
          hbuf[par^1][b][wv*32 + hh*16 + c16] = f2bf(hv);
        }
      }
    }
    ah0 = *(const bf16x8*)(&hbuf[par^1][hrow][0] + co[0]);  // own chunk, intra-wave
    ax = axn;
    __syncthreads();
    par ^= 1;
  }

  // ---------------- decoder ----------------
#pragma unroll
  for (int hh=0;hh<2;++hh){
    int col = wv*32 + hh*16 + c16;
    bi [hh] = (dbih[0*Hsz+col]+dbhh[0*Hsz+col])*LOG2E;
    bff[hh] = (dbih[1*Hsz+col]+dbhh[1*Hsz+col])*LOG2E;
    bgg[hh] = (dbih[2*Hsz+col]+dbhh[2*Hsz+col])*(2.f*LOG2E);
    bo [hh] = (dbih[3*Hsz+col]+dbhh[3*Hsz+col])*LOG2E;
  }

  // step 0: gates = enc_h @ dWhh^T + b  (cell stays enc_c from here on)
#pragma unroll
  for (int j=0;j<8;++j){
    int g = j>>1;
    int n = g*128 + wv*32 + (j&1)*16 + c16;
    float s = (g==2) ? 2.f*LOG2E : LOG2E;
#pragma unroll
    for (int m=0;m<4;++m)
      W[j][m] = ldw(dWhh + (size_t)n*Hsz + ((wv+m)&3)*32 + quad*8, s);
  }
  {
    const unsigned short* hp = &hbuf[par][hrow][0];
    bf16x8 ah1 = *(const bf16x8*)(hp + co[1]);
    bf16x8 ah2 = *(const bf16x8*)(hp + co[2]);
    bf16x8 ah3 = *(const bf16x8*)(hp + co[3]);
    f32x4 acc[8];
#pragma unroll
    for (int j=0;j<8;++j) acc[j] = __builtin_amdgcn_mfma_f32_16x16x32_bf16(ah0, W[j][0], zero4, 0,0,0);
#pragma unroll
    for (int j=0;j<8;++j) acc[j] = __builtin_amdgcn_mfma_f32_16x16x32_bf16(ah1, W[j][1], acc[j], 0,0,0);
#pragma unroll
    for (int j=0;j<8;++j) acc[j] = __builtin_amdgcn_mfma_f32_16x16x32_bf16(ah2, W[j][2], acc[j], 0,0,0);
#pragma unroll
    for (int j=0;j<8;++j) acc[j] = __builtin_amdgcn_mfma_f32_16x16x32_bf16(ah3, W[j][3], acc[j], 0,0,0);
    if (quad == 0){
#pragma unroll
      for (int hh=0;hh<2;++hh){
#pragma unroll
        for (int b=0;b<2;++b){
          float pi = acc[0+hh][b] + bi [hh];
          float pf = acc[2+hh][b] + bff[hh];
          float pg = acc[4+hh][b] + bgg[hh];
          float po = acc[6+hh][b] + bo [hh];
          float iv=sigm_p(pi), fv=sigm_p(pf), ov=sigm_p(po), gv=tanh_p(pg);
          float cn = fv*cst[hh*2+b] + iv*gv;     // no update: cell stays enc_c
          float hv = ov * tanh_p(cn*(2.f*LOG2E));
          hbuf[par^1][b][wv*32 + hh*16 + c16] = f2bf(hv);
        }
      }
    }
    ah0 = *(const bf16x8*)(&hbuf[par^1][hrow][0] + co[0]);
    __syncthreads();
    par ^= 1;
  }

  // steps >=1: inp == h -> W = (dWih + dWhh);  fc tiles on waves 2,3
#pragma unroll
  for (int j=0;j<8;++j){
    int g = j>>1;
    int n = g*128 + wv*32 + (j&1)*16 + c16;
    float s = (g==2) ? 2.f*LOG2E : LOG2E;
#pragma unroll
    for (int m=0;m<4;++m){
      int ko = ((wv+m)&3)*32 + quad*8;
      W[j][m] = ldws(dWih + (size_t)n*Hsz + ko, dWhh + (size_t)n*Hsz + ko, s);
    }
  }
  bf16x8 wf[4];
  f32x4 biasf4 = {0.f,0.f,0.f,0.f};
  if (wv >= 2){
    int n = (wv-2)*16 + c16;
#pragma unroll
    for (int m=0;m<4;++m)
      wf[m] = ldw(fcW + (size_t)n*Hsz + ((wv+m)&3)*32 + quad*8, 1.f);
    float bfc = fcb[n];
    biasf4[0]=bfc; biasf4[1]=bfc; biasf4[2]=bfc; biasf4[3]=bfc;
  }
  float* fr = big;   // frames fp32: [b][t*32 + n]

  for (int t=1; t<Ssz; ++t){
    const unsigned short* hp = &hbuf[par][hrow][0];
    bf16x8 ah1 = *(const bf16x8*)(hp + co[1]);
    bf16x8 ah2 = *(const bf16x8*)(hp + co[2]);
    bf16x8 ah3 = *(const bf16x8*)(hp + co[3]);
    f32x4 acc[8];
    f32x4 fa;
#pragma unroll
    for (int j=0;j<8;++j) acc[j] = __builtin_amdgcn_mfma_f32_16x16x32_bf16(ah0, W[j][0], zero4, 0,0,0);
    if (wv >= 2) fa = __builtin_amdgcn_mfma_f32_16x16x32_bf16(ah0, wf[0], biasf4, 0,0,0);
#pragma unroll
    for (int j=0;j<8;++j) acc[j] = __builtin_amdgcn_mfma_f32_16x16x32_bf16(ah1, W[j][1], acc[j], 0,0,0);
    if (wv >= 2) fa = __builtin_amdgcn_mfma_f32_16x16x32_bf16(ah1, wf[1], fa, 0,0,0);
#pragma unroll
    for (int j=0;j<8;++j) acc[j] = __builtin_amdgcn_mfma_f32_16x16x32_bf16(ah2, W[j][2], acc[j], 0,0,0);
    if (wv >= 2) fa = __builtin_amdgcn_mfma_f32_16x16x32_bf16(ah2, wf[2], fa, 0,0,0);
#pragma unroll
    for (int j=0;j<8;++j) acc[j] = __builtin_amdgcn_mfma_f32_16x16x32_bf16(ah3, W[j][3], acc[j], 0,0,0);
    if (wv >= 2){
      fa = __builtin_amdgcn_mfma_f32_16x16x32_bf16(ah3, wf[3], fa, 0,0,0);
      if (quad == 0){
        fr[          (t-1)*Isz + (wv-2)*16 + c16] = fa[0];
        fr[Ssz*Isz + (t-1)*Isz + (wv-2)*16 + c16] = fa[1];
      }
    }
    if (quad == 0){
#pragma unroll
      for (int hh=0;hh<2;++hh){
#pragma unroll
        for (int b=0;b<2;++b){
          float pi = acc[0+hh][b] + bi [hh];
          float pf = acc[2+hh][b] + bff[hh];
          float pg = acc[4+hh][b] + bgg[hh];
          float po = acc[6+hh][b] + bo [hh];
          float iv=sigm_p(pi), fv=sigm_p(pf), ov=sigm_p(po), gv=tanh_p(pg);
          float cn = fv*cst[hh*2+b] + iv*gv;
          float hv = ov * tanh_p(cn*(2.f*LOG2E));
          hbuf[par^1][b][wv*32 + hh*16 + c16] = f2bf(hv);
        }
      }
    }
    ah0 = *(const bf16x8*)(&hbuf[par^1][hrow][0] + co[0]);
    __syncthreads();
    par ^= 1;
  }

  // epilogue: frame s=511 from h(511) (in hbuf[par])
  {
    const unsigned short* hp = &hbuf[par][hrow][0];
    if (wv >= 2){
      bf16x8 b0 = *(const bf16x8*)(hp + co[0]);
      bf16x8 b1 = *(const bf16x8*)(hp + co[1]);
      bf16x8 b2 = *(const bf16x8*)(hp + co[2]);
      bf16x8 b3 = *(const bf16x8*)(hp + co[3]);
      f32x4 fa = __builtin_amdgcn_mfma_f32_16x16x32_bf16(b0, wf[0], biasf4, 0,0,0);
      fa = __builtin_amdgcn_mfma_f32_16x16x32_bf16(b1, wf[1], fa, 0,0,0);
      fa = __builtin_amdgcn_mfma_f32_16x16x32_bf16(b2, wf[2], fa, 0,0,0);
      fa = __builtin_amdgcn_mfma_f32_16x16x32_bf16(b3, wf[3], fa, 0,0,0);
      if (quad == 0){
        fr[          (Ssz-1)*Isz + (wv-2)*16 + c16] = fa[0];
        fr[Ssz*Isz + (Ssz-1)*Isz + (wv-2)*16 + c16] = fa[1];
      }
    }
  }
  __syncthreads();

  // bulk coalesced frame store
#pragma unroll 4
  for (int i = tid*4; i < 2*Ssz*Isz; i += 256*4){
    f32x4 v = *(const f32x4*)(big + i);
    *(f32x4*)(out + (size_t)(bg0 + (i>>14))*(Ssz*Isz) + (i & 16383)) = v;
  }
}

extern "C" void kernel_launch(void* const* d_in, const int* in_sizes, int n_in,
                              void* d_out, int out_size, void* d_ws, size_t ws_size,
                              hipStream_t stream) {
  const float* x    = (const float*)d_in[0];
  const float* eWih = (const float*)d_in[1];
  const float* eWhh = (const float*)d_in[2];
  const float* ebih = (const float*)d_in[3];
  const float* ebhh = (const float*)d_in[4];
  const float* dWih = (const float*)d_in[5];
  const float* dWhh = (const float*)d_in[6];
  const float* dbih = (const float*)d_in[7];
  const float* dbhh = (const float*)d_in[8];
  const float* fcW  = (const float*)d_in[9];
  const float* fcb  = (const float*)d_in[10];
  float* outp = (float*)d_out;
  (void)d_ws; (void)ws_size; (void)in_sizes; (void)n_in; (void)out_size;
  lstm_ae<<<dim3(Bsz/BB), dim3(256), 0, stream>>>(
      x, eWih, eWhh, ebih, ebhh, dWih, dWhh, dbih, dbhh, fcW, fcb, outp);
}

// Round 5
// 732.843 us; speedup vs baseline: 1.1950x; 1.1950x over previous
//
#include <hip/hip_runtime.h>

#define Bsz 512
#define Ssz 512
#define Isz 32
#define Hsz 128
#define BB  2
#define NT  512   // threads/WG = 8 waves, 2 per SIMD
#define LOG2E 1.44269504088896340736f

typedef __attribute__((ext_vector_type(8))) short bf16x8;
typedef __attribute__((ext_vector_type(4))) float f32x4;

__device__ __forceinline__ unsigned short f2bf(float f){
  unsigned u = __float_as_uint(f);
  return (unsigned short)((u + 0x7FFFu + ((u >> 16) & 1u)) >> 16);
}
__device__ __forceinline__ float sigm_p(float xp){          // pre-scaled by log2e
  return __builtin_amdgcn_rcpf(1.f + __builtin_amdgcn_exp2f(-xp));
}
__device__ __forceinline__ float tanh_p(float xp2){         // pre-scaled by 2*log2e
  return 1.f - 2.f * __builtin_amdgcn_rcpf(1.f + __builtin_amdgcn_exp2f(xp2));
}
__device__ __forceinline__ bf16x8 ldw(const float* p, float s){
  bf16x8 r;
#pragma unroll
  for (int e=0;e<8;++e) r[e] = (short)f2bf(p[e]*s);
  return r;
}
__device__ __forceinline__ bf16x8 ldws(const float* pa, const float* pb, float s){
  bf16x8 r;
#pragma unroll
  for (int e=0;e<8;++e) r[e] = (short)f2bf((pa[e]+pb[e])*s);
  return r;
}

__global__ __launch_bounds__(NT, 2) void lstm_ae(
    const float* __restrict__ x,
    const float* __restrict__ eWih, const float* __restrict__ eWhh,
    const float* __restrict__ ebih, const float* __restrict__ ebhh,
    const float* __restrict__ dWih, const float* __restrict__ dWhh,
    const float* __restrict__ dbih, const float* __restrict__ dbhh,
    const float* __restrict__ fcW,  const float* __restrict__ fcb,
    float* __restrict__ out)
{
  __shared__ __attribute__((aligned(16))) float big[2*Ssz*Isz];   // x bf16 / frames f32
  __shared__ __attribute__((aligned(16))) unsigned short hbuf[2][2][136];

  const int tid  = threadIdx.x;
  const int lane = tid & 63;
  const int wv   = tid >> 6;          // 0..7: owns cols 16wv..16wv+15, all 4 gates
  const int c16  = lane & 15;
  const int quad = lane >> 4;
  const int bg0  = blockIdx.x * BB;
  const int hrow = c16 & 1;           // A-frag row source (rows>=2 duplicate)
  const int col  = wv*16 + c16;       // this lane's h/gate column

  // ---- stage x as bf16 into LDS ----
  unsigned short* xl = (unsigned short*)big;
#pragma unroll 2
  for (int i = tid*4; i < 2*Ssz*Isz; i += NT*4){
    f32x4 v = *(const f32x4*)(x + (size_t)(bg0 + (i>>14))*(Ssz*Isz) + (i & 16383));
    xl[i+0]=f2bf(v[0]); xl[i+1]=f2bf(v[1]); xl[i+2]=f2bf(v[2]); xl[i+3]=f2bf(v[3]);
  }
  for (int i = tid; i < 2*2*136; i += NT) ((unsigned short*)hbuf)[i] = 0;

  // chunk slot m -> K-chunk (wv+m)&3 (stagger LDS access across waves)
  int co[4];
#pragma unroll
  for (int m=0;m<4;++m) co[m] = ((wv+m)&3)*32 + quad*8;

  // ---- encoder weights -> registers ----
  bf16x8 W[4][4], wx[4];
#pragma unroll
  for (int g=0;g<4;++g){
    int n = g*128 + col;
    float s = (g==2) ? 2.f*LOG2E : LOG2E;
#pragma unroll
    for (int m=0;m<4;++m)
      W[g][m] = ldw(eWhh + (size_t)n*Hsz + ((wv+m)&3)*32 + quad*8, s);
    wx[g] = ldw(eWih + (size_t)n*Isz + quad*8, s);
  }
  float b_i = (ebih[0*Hsz+col]+ebhh[0*Hsz+col])*LOG2E;
  float b_f = (ebih[1*Hsz+col]+ebhh[1*Hsz+col])*LOG2E;
  float b_g = (ebih[2*Hsz+col]+ebhh[2*Hsz+col])*(2.f*LOG2E);
  float b_o = (ebih[3*Hsz+col]+ebhh[3*Hsz+col])*LOG2E;

  const f32x4 zero4 = {0.f,0.f,0.f,0.f};
  float cst[2] = {0.f,0.f};           // cell state rows 0,1 at this col (quad0)

  __syncthreads();

  int par = 0;

  // ---------------- encoder ----------------
  for (int t=0; t<Ssz; ++t){
    const unsigned short* hp = &hbuf[par][hrow][0];
    bf16x8 ah[4];
#pragma unroll
    for (int m=0;m<4;++m) ah[m] = *(const bf16x8*)(hp + co[m]);
    bf16x8 ax = *(const bf16x8*)(xl + hrow*(Ssz*Isz) + t*Isz + quad*8);
    f32x4 acc[4];
#pragma unroll
    for (int g=0;g<4;++g) acc[g] = __builtin_amdgcn_mfma_f32_16x16x32_bf16(ax, wx[g], zero4, 0,0,0);
#pragma unroll
    for (int m=0;m<4;++m)
#pragma unroll
      for (int g=0;g<4;++g)
        acc[g] = __builtin_amdgcn_mfma_f32_16x16x32_bf16(ah[m], W[g][m], acc[g], 0,0,0);
    if (quad == 0){
#pragma unroll
      for (int b=0;b<2;++b){
        float pi = acc[0][b] + b_i;
        float pf = acc[1][b] + b_f;
        float pg = acc[2][b] + b_g;
        float po = acc[3][b] + b_o;
        float iv=sigm_p(pi), fv=sigm_p(pf), ov=sigm_p(po), gv=tanh_p(pg);
        float cn = fv*cst[b] + iv*gv;
        cst[b] = cn;
        float hv = ov * tanh_p(cn*(2.f*LOG2E));
        hbuf[par^1][b][col] = f2bf(hv);
      }
    }
    __syncthreads();
    par ^= 1;
  }

  // ---------------- decoder ----------------
  b_i = (dbih[0*Hsz+col]+dbhh[0*Hsz+col])*LOG2E;
  b_f = (dbih[1*Hsz+col]+dbhh[1*Hsz+col])*LOG2E;
  b_g = (dbih[2*Hsz+col]+dbhh[2*Hsz+col])*(2.f*LOG2E);
  b_o = (dbih[3*Hsz+col]+dbhh[3*Hsz+col])*LOG2E;

  // step 0: gates = enc_h @ dWhh^T + b  (cell stays enc_c from here on)
#pragma unroll
  for (int g=0;g<4;++g){
    int n = g*128 + col;
    float s = (g==2) ? 2.f*LOG2E : LOG2E;
#pragma unroll
    for (int m=0;m<4;++m)
      W[g][m] = ldw(dWhh + (size_t)n*Hsz + ((wv+m)&3)*32 + quad*8, s);
  }
  {
    const unsigned short* hp = &hbuf[par][hrow][0];
    bf16x8 ah[4];
#pragma unroll
    for (int m=0;m<4;++m) ah[m] = *(const bf16x8*)(hp + co[m]);
    f32x4 acc[4];
#pragma unroll
    for (int g=0;g<4;++g) acc[g] = __builtin_amdgcn_mfma_f32_16x16x32_bf16(ah[0], W[g][0], zero4, 0,0,0);
#pragma unroll
    for (int m=1;m<4;++m)
#pragma unroll
      for (int g=0;g<4;++g)
        acc[g] = __builtin_amdgcn_mfma_f32_16x16x32_bf16(ah[m], W[g][m], acc[g], 0,0,0);
    if (quad == 0){
#pragma unroll
      for (int b=0;b<2;++b){
        float pi = acc[0][b] + b_i;
        float pf = acc[1][b] + b_f;
        float pg = acc[2][b] + b_g;
        float po = acc[3][b] + b_o;
        float iv=sigm_p(pi), fv=sigm_p(pf), ov=sigm_p(po), gv=tanh_p(pg);
        float cn = fv*cst[b] + iv*gv;            // no update: cell stays enc_c
        float hv = ov * tanh_p(cn*(2.f*LOG2E));
        hbuf[par^1][b][col] = f2bf(hv);
      }
    }
    __syncthreads();
    par ^= 1;
  }

  // steps >=1: inp == h -> W = (dWih + dWhh); fc tiles on waves 6,7
#pragma unroll
  for (int g=0;g<4;++g){
    int n = g*128 + col;
    float s = (g==2) ? 2.f*LOG2E : LOG2E;
#pragma unroll
    for (int m=0;m<4;++m){
      int ko = ((wv+m)&3)*32 + quad*8;
      W[g][m] = ldws(dWih + (size_t)n*Hsz + ko, dWhh + (size_t)n*Hsz + ko, s);
    }
  }
  bf16x8 wf[4];
  f32x4 biasf4 = {0.f,0.f,0.f,0.f};
  if (wv >= 6){
    int n = (wv-6)*16 + c16;
#pragma unroll
    for (int m=0;m<4;++m)
      wf[m] = ldw(fcW + (size_t)n*Hsz + ((wv+m)&3)*32 + quad*8, 1.f);
    float bfc = fcb[n];
    biasf4[0]=bfc; biasf4[1]=bfc; biasf4[2]=bfc; biasf4[3]=bfc;
  }
  float* fr = big;   // frames fp32: [b][t*32 + n]

  for (int t=1; t<Ssz; ++t){
    const unsigned short* hp = &hbuf[par][hrow][0];
    bf16x8 ah[4];
#pragma unroll
    for (int m=0;m<4;++m) ah[m] = *(const bf16x8*)(hp + co[m]);
    f32x4 acc[4];
    f32x4 fa;
#pragma unroll
    for (int g=0;g<4;++g) acc[g] = __builtin_amdgcn_mfma_f32_16x16x32_bf16(ah[0], W[g][0], zero4, 0,0,0);
    if (wv >= 6) fa = __builtin_amdgcn_mfma_f32_16x16x32_bf16(ah[0], wf[0], biasf4, 0,0,0);
#pragma unroll
    for (int m=1;m<4;++m){
#pragma unroll
      for (int g=0;g<4;++g)
        acc[g] = __builtin_amdgcn_mfma_f32_16x16x32_bf16(ah[m], W[g][m], acc[g], 0,0,0);
      if (wv >= 6) fa = __builtin_amdgcn_mfma_f32_16x16x32_bf16(ah[m], wf[m], fa, 0,0,0);
    }
    if (wv >= 6 && quad == 0){
      fr[          (t-1)*Isz + (wv-6)*16 + c16] = fa[0];
      fr[Ssz*Isz + (t-1)*Isz + (wv-6)*16 + c16] = fa[1];
    }
    if (quad == 0){
#pragma unroll
      for (int b=0;b<2;++b){
        float pi = acc[0][b] + b_i;
        float pf = acc[1][b] + b_f;
        float pg = acc[2][b] + b_g;
        float po = acc[3][b] + b_o;
        float iv=sigm_p(pi), fv=sigm_p(pf), ov=sigm_p(po), gv=tanh_p(pg);
        float cn = fv*cst[b] + iv*gv;
        float hv = ov * tanh_p(cn*(2.f*LOG2E));
        hbuf[par^1][b][col] = f2bf(hv);
      }
    }
    __syncthreads();
    par ^= 1;
  }

  // epilogue: frame s=511 from h(511) (in hbuf[par])
  if (wv >= 6){
    const unsigned short* hp = &hbuf[par][hrow][0];
    bf16x8 ah[4];
#pragma unroll
    for (int m=0;m<4;++m) ah[m] = *(const bf16x8*)(hp + co[m]);
    f32x4 fa = __builtin_amdgcn_mfma_f32_16x16x32_bf16(ah[0], wf[0], biasf4, 0,0,0);
#pragma unroll
    for (int m=1;m<4;++m)
      fa = __builtin_amdgcn_mfma_f32_16x16x32_bf16(ah[m], wf[m], fa, 0,0,0);
    if (quad == 0){
      fr[          (Ssz-1)*Isz + (wv-6)*16 + c16] = fa[0];
      fr[Ssz*Isz + (Ssz-1)*Isz + (wv-6)*16 + c16] = fa[1];
    }
  }
  __syncthreads();

  // bulk coalesced frame store
#pragma unroll 2
  for (int i = tid*4; i < 2*Ssz*Isz; i += NT*4){
    f32x4 v = *(const f32x4*)(big + i);
    *(f32x4*)(out + (size_t)(bg0 + (i>>14))*(Ssz*Isz) + (i & 16383)) = v;
  }
}

extern "C" void kernel_launch(void* const* d_in, const int* in_sizes, int n_in,
                              void* d_out, int out_size, void* d_ws, size_t ws_size,
                              hipStream_t stream) {
  const float* x    = (const float*)d_in[0];
  const float* eWih = (const float*)d_in[1];
  const float* eWhh = (const float*)d_in[2];
  const float* ebih = (const float*)d_in[3];
  const float* ebhh = (const float*)d_in[4];
  const float* dWih = (const float*)d_in[5];
  const float* dWhh = (const float*)d_in[6];
  const float* dbih = (const float*)d_in[7];
  const float* dbhh = (const float*)d_in[8];
  const float* fcW  = (const float*)d_in[9];
  const float* fcb  = (const float*)d_in[10];
  float* outp = (float*)d_out;
  (void)d_ws; (void)ws_size; (void)in_sizes; (void)n_in; (void)out_size;
  lstm_ae<<<dim3(Bsz/BB), dim3(NT), 0, stream>>>(
      x, eWih, eWhh, ebih, ebhh, dWih, dWhh, dbih, dbhh, fcW, fcb, outp);
}

// Round 6
// 593.243 us; speedup vs baseline: 1.4762x; 1.2353x over previous
//
#include <hip/hip_runtime.h>

#define Bsz 512
#define Ssz 512
#define Isz 32
#define Hsz 128
#define BB  2
#define NT  512   // 8 waves, 2 per SIMD
#define LOG2E 1.44269504088896340736f

typedef __attribute__((ext_vector_type(8))) short bf16x8;
typedef __attribute__((ext_vector_type(4))) float f32x4;

__device__ __forceinline__ unsigned short f2bf(float f){
  unsigned u = __float_as_uint(f);
  return (unsigned short)((u + 0x7FFFu + ((u >> 16) & 1u)) >> 16);
}
__device__ __forceinline__ float sigm_p(float xp){          // pre-scaled by log2e
  return __builtin_amdgcn_rcpf(1.f + __builtin_amdgcn_exp2f(-xp));
}
__device__ __forceinline__ float tanh_p(float xp2){         // pre-scaled by 2*log2e
  return 1.f - 2.f * __builtin_amdgcn_rcpf(1.f + __builtin_amdgcn_exp2f(xp2));
}
__device__ __forceinline__ bf16x8 ldw(const float* p, float s){
  bf16x8 r;
#pragma unroll
  for (int e=0;e<8;++e) r[e] = (short)f2bf(p[e]*s);
  return r;
}
__device__ __forceinline__ bf16x8 ldws(const float* pa, const float* pb, float s){
  bf16x8 r;
#pragma unroll
  for (int e=0;e<8;++e) r[e] = (short)f2bf((pa[e]+pb[e])*s);
  return r;
}

__global__ __launch_bounds__(NT, 2) void lstm_ae(
    const float* __restrict__ x,
    const float* __restrict__ eWih, const float* __restrict__ eWhh,
    const float* __restrict__ ebih, const float* __restrict__ ebhh,
    const float* __restrict__ dWih, const float* __restrict__ dWhh,
    const float* __restrict__ dbih, const float* __restrict__ dbhh,
    const float* __restrict__ fcW,  const float* __restrict__ fcb,
    float* __restrict__ out)
{
  __shared__ __attribute__((aligned(16))) float big[2*Ssz*Isz];   // x bf16 / frames f32
  __shared__ __attribute__((aligned(16))) unsigned short hbuf[2][2][136];

  const int tid  = threadIdx.x;
  const int lane = tid & 63;
  const int wv   = tid >> 6;          // owns cols 16wv..16wv+15, all 4 gates
  const int c16  = lane & 15;
  const int quad = lane >> 4;
  const int bg0  = blockIdx.x * BB;
  const int hrow = (c16 >> 2) & 1;    // batch rows at A-rows 0 and 4 -> C rows 0(q0),4(q1)
  const int col  = wv*16 + c16;

  // ---- stage x as bf16 into LDS ----
  unsigned short* xl = (unsigned short*)big;
#pragma unroll 2
  for (int i = tid*4; i < 2*Ssz*Isz; i += NT*4){
    f32x4 v = *(const f32x4*)(x + (size_t)(bg0 + (i>>14))*(Ssz*Isz) + (i & 16383));
    xl[i+0]=f2bf(v[0]); xl[i+1]=f2bf(v[1]); xl[i+2]=f2bf(v[2]); xl[i+3]=f2bf(v[3]);
  }
  for (int i = tid; i < 2*2*136; i += NT) ((unsigned short*)hbuf)[i] = 0;

  // ---- encoder weights -> registers ----
  bf16x8 W[4][4], wx[4];
#pragma unroll
  for (int g=0;g<4;++g){
    int n = g*128 + col;
    float s = (g==2) ? 2.f*LOG2E : LOG2E;
#pragma unroll
    for (int m=0;m<4;++m) W[g][m] = ldw(eWhh + (size_t)n*Hsz + m*32 + quad*8, s);
    wx[g] = ldw(eWih + (size_t)n*Isz + quad*8, s);
  }
  float b_i = (ebih[0*Hsz+col]+ebhh[0*Hsz+col])*LOG2E;
  float b_f = (ebih[1*Hsz+col]+ebhh[1*Hsz+col])*LOG2E;
  float b_g = (ebih[2*Hsz+col]+ebhh[2*Hsz+col])*(2.f*LOG2E);
  float b_o = (ebih[3*Hsz+col]+ebhh[3*Hsz+col])*LOG2E;

  const f32x4 zero4 = {0.f,0.f,0.f,0.f};
  float cst = 0.f;                    // cell state (quads 0,1: batch row = quad)

  // precomputed lane pointers (all per-step LDS addressing via immediates)
  const unsigned short* rd0 = &hbuf[0][hrow][0] + quad*8;   // read h when in par 0
  const unsigned short* rd1 = &hbuf[1][hrow][0] + quad*8;
  unsigned short* wr0 = &hbuf[1][quad&1][col];              // write target from par 0
  unsigned short* wr1 = &hbuf[0][quad&1][col];

  auto act = [&](const f32x4* acc, unsigned short* wp, bool upd){
    if (quad < 2){
      float pi = acc[0][0] + b_i;
      float pf = acc[1][0] + b_f;
      float pg = acc[2][0] + b_g;
      float po = acc[3][0] + b_o;
      float iv=sigm_p(pi), fv=sigm_p(pf), ov=sigm_p(po), gv=tanh_p(pg);
      float cn = fv*cst + iv*gv;
      if (upd) cst = cn;
      *wp = f2bf(ov * tanh_p(cn*(2.f*LOG2E)));
    }
  };

  auto ebody = [&](const unsigned short* rd, unsigned short* wp,
                   f32x4* acc, f32x4* acc2, bf16x8 axn, const unsigned short* xp)->bf16x8{
    bf16x8 a0 = *(const bf16x8*)(rd);
    bf16x8 a1 = *(const bf16x8*)(rd+32);
    bf16x8 a2 = *(const bf16x8*)(rd+64);
    bf16x8 a3 = *(const bf16x8*)(rd+96);
#pragma unroll
    for (int g=0;g<4;++g) acc[g] = __builtin_amdgcn_mfma_f32_16x16x32_bf16(a0, W[g][0], acc[g], 0,0,0);
#pragma unroll
    for (int g=0;g<4;++g) acc[g] = __builtin_amdgcn_mfma_f32_16x16x32_bf16(a1, W[g][1], acc[g], 0,0,0);
#pragma unroll
    for (int g=0;g<4;++g) acc[g] = __builtin_amdgcn_mfma_f32_16x16x32_bf16(a2, W[g][2], acc[g], 0,0,0);
#pragma unroll
    for (int g=0;g<4;++g) acc[g] = __builtin_amdgcn_mfma_f32_16x16x32_bf16(a3, W[g][3], acc[g], 0,0,0);
    // next step's x contribution: fills pipe during act/barrier tail
#pragma unroll
    for (int g=0;g<4;++g) acc2[g] = __builtin_amdgcn_mfma_f32_16x16x32_bf16(axn, wx[g], zero4, 0,0,0);
    act(acc, wp, true);
    bf16x8 ax2 = *(const bf16x8*)(xp);
    __syncthreads();
    return ax2;
  };

  __syncthreads();   // x staged, hbuf[0] zeroed

  // ---------------- encoder (512 steps, unrolled x2) ----------------
  const unsigned short* xq = xl + hrow*(Ssz*Isz) + quad*8;
  bf16x8 ax0 = *(const bf16x8*)(xq);
  bf16x8 axn = *(const bf16x8*)(xq + 32);
  f32x4 A_[4], B_[4];
#pragma unroll
  for (int g=0;g<4;++g) A_[g] = __builtin_amdgcn_mfma_f32_16x16x32_bf16(ax0, wx[g], zero4, 0,0,0);
  const unsigned short* xp = xq + 64;
  for (int it=0; it<Ssz/2; ++it){
    axn = ebody(rd0, wr0, A_, B_, axn, xp); xp += 32;
    axn = ebody(rd1, wr1, B_, A_, axn, xp); xp += 32;
  }

  // ---------------- decoder ----------------
  b_i = (dbih[0*Hsz+col]+dbhh[0*Hsz+col])*LOG2E;
  b_f = (dbih[1*Hsz+col]+dbhh[1*Hsz+col])*LOG2E;
  b_g = (dbih[2*Hsz+col]+dbhh[2*Hsz+col])*(2.f*LOG2E);
  b_o = (dbih[3*Hsz+col]+dbhh[3*Hsz+col])*LOG2E;

  // step 0: gates = enc_h @ dWhh^T + b (cell stays enc_c; enc_h in hbuf[0])
#pragma unroll
  for (int g=0;g<4;++g){
    int n = g*128 + col;
    float s = (g==2) ? 2.f*LOG2E : LOG2E;
#pragma unroll
    for (int m=0;m<4;++m) W[g][m] = ldw(dWhh + (size_t)n*Hsz + m*32 + quad*8, s);
  }
  {
    bf16x8 a0 = *(const bf16x8*)(rd0);
    bf16x8 a1 = *(const bf16x8*)(rd0+32);
    bf16x8 a2 = *(const bf16x8*)(rd0+64);
    bf16x8 a3 = *(const bf16x8*)(rd0+96);
    f32x4 acc[4];
#pragma unroll
    for (int g=0;g<4;++g) acc[g] = __builtin_amdgcn_mfma_f32_16x16x32_bf16(a0, W[g][0], zero4, 0,0,0);
#pragma unroll
    for (int g=0;g<4;++g) acc[g] = __builtin_amdgcn_mfma_f32_16x16x32_bf16(a1, W[g][1], acc[g], 0,0,0);
#pragma unroll
    for (int g=0;g<4;++g) acc[g] = __builtin_amdgcn_mfma_f32_16x16x32_bf16(a2, W[g][2], acc[g], 0,0,0);
#pragma unroll
    for (int g=0;g<4;++g) acc[g] = __builtin_amdgcn_mfma_f32_16x16x32_bf16(a3, W[g][3], acc[g], 0,0,0);
    act(acc, wr0, false);
    __syncthreads();
  }

  // steps >=1: W = (dWih + dWhh); fc on waves 6,7
#pragma unroll
  for (int g=0;g<4;++g){
    int n = g*128 + col;
    float s = (g==2) ? 2.f*LOG2E : LOG2E;
#pragma unroll
    for (int m=0;m<4;++m){
      const float* pa = dWih + (size_t)n*Hsz + m*32 + quad*8;
      const float* pb = dWhh + (size_t)n*Hsz + m*32 + quad*8;
      W[g][m] = ldws(pa, pb, s);
    }
  }
  bf16x8 wf[4];
  f32x4 biasf4 = {0.f,0.f,0.f,0.f};
  if (wv >= 6){
    int n = (wv-6)*16 + c16;
#pragma unroll
    for (int m=0;m<4;++m) wf[m] = ldw(fcW + (size_t)n*Hsz + m*32 + quad*8, 1.f);
    float bfc = fcb[n];
    biasf4[0]=bfc; biasf4[1]=bfc; biasf4[2]=bfc; biasf4[3]=bfc;
  }
  const int nf = (wv >= 6) ? (wv-6)*16 + c16 : 0;
  float* fp = big + quad*(Ssz*Isz) + nf;   // frame(t-1) slot, advanced +32/step

  auto dbody = [&](const unsigned short* rd, unsigned short* wp, float* fpp){
    bf16x8 a0 = *(const bf16x8*)(rd);
    bf16x8 a1 = *(const bf16x8*)(rd+32);
    bf16x8 a2 = *(const bf16x8*)(rd+64);
    bf16x8 a3 = *(const bf16x8*)(rd+96);
    f32x4 acc[4];
#pragma unroll
    for (int g=0;g<4;++g) acc[g] = __builtin_amdgcn_mfma_f32_16x16x32_bf16(a0, W[g][0], zero4, 0,0,0);
#pragma unroll
    for (int g=0;g<4;++g) acc[g] = __builtin_amdgcn_mfma_f32_16x16x32_bf16(a1, W[g][1], acc[g], 0,0,0);
#pragma unroll
    for (int g=0;g<4;++g) acc[g] = __builtin_amdgcn_mfma_f32_16x16x32_bf16(a2, W[g][2], acc[g], 0,0,0);
#pragma unroll
    for (int g=0;g<4;++g) acc[g] = __builtin_amdgcn_mfma_f32_16x16x32_bf16(a3, W[g][3], acc[g], 0,0,0);
    if (wv >= 6){
      f32x4 fa = __builtin_amdgcn_mfma_f32_16x16x32_bf16(a0, wf[0], biasf4, 0,0,0);
      fa = __builtin_amdgcn_mfma_f32_16x16x32_bf16(a1, wf[1], fa, 0,0,0);
      fa = __builtin_amdgcn_mfma_f32_16x16x32_bf16(a2, wf[2], fa, 0,0,0);
      fa = __builtin_amdgcn_mfma_f32_16x16x32_bf16(a3, wf[3], fa, 0,0,0);
      act(acc, wp, false);
      if (quad < 2) *fpp = fa[0];
    } else {
      act(acc, wp, false);
    }
    __syncthreads();
  };

  // t = 1..510 (255 pairs), then t = 511
  for (int it=0; it<255; ++it){
    dbody(rd1, wr1, fp); fp += 32;
    dbody(rd0, wr0, fp); fp += 32;
  }
  dbody(rd1, wr1, fp); fp += 32;     // t=511, stores frame 510

  // epilogue: frame 511 from h(511) (in hbuf[0])
  if (wv >= 6){
    bf16x8 a0 = *(const bf16x8*)(rd0);
    bf16x8 a1 = *(const bf16x8*)(rd0+32);
    bf16x8 a2 = *(const bf16x8*)(rd0+64);
    bf16x8 a3 = *(const bf16x8*)(rd0+96);
    f32x4 fa = __builtin_amdgcn_mfma_f32_16x16x32_bf16(a0, wf[0], biasf4, 0,0,0);
    fa = __builtin_amdgcn_mfma_f32_16x16x32_bf16(a1, wf[1], fa, 0,0,0);
    fa = __builtin_amdgcn_mfma_f32_16x16x32_bf16(a2, wf[2], fa, 0,0,0);
    fa = __builtin_amdgcn_mfma_f32_16x16x32_bf16(a3, wf[3], fa, 0,0,0);
    if (quad < 2) *fp = fa[0];
  }
  __syncthreads();

  // bulk coalesced frame store
#pragma unroll 2
  for (int i = tid*4; i < 2*Ssz*Isz; i += NT*4){
    f32x4 v = *(const f32x4*)(big + i);
    *(f32x4*)(out + (size_t)(bg0 + (i>>14))*(Ssz*Isz) + (i & 16383)) = v;
  }
}

extern "C" void kernel_launch(void* const* d_in, const int* in_sizes, int n_in,
                              void* d_out, int out_size, void* d_ws, size_t ws_size,
                              hipStream_t stream) {
  const float* x    = (const float*)d_in[0];
  const float* eWih = (const float*)d_in[1];
  const float* eWhh = (const float*)d_in[2];
  const float* ebih = (const float*)d_in[3];
  const float* ebhh = (const float*)d_in[4];
  const float* dWih = (const float*)d_in[5];
  const float* dWhh = (const float*)d_in[6];
  const float* dbih = (const float*)d_in[7];
  const float* dbhh = (const float*)d_in[8];
  const float* fcW  = (const float*)d_in[9];
  const float* fcb  = (const float*)d_in[10];
  float* outp = (float*)d_out;
  (void)d_ws; (void)ws_size; (void)in_sizes; (void)n_in; (void)out_size;
  lstm_ae<<<dim3(Bsz/BB), dim3(NT), 0, stream>>>(
      x, eWih, eWhh, ebih, ebhh, dWih, dWhh, dbih, dbhh, fcW, fcb, outp);
}